// Round 8
// baseline (388.719 us; speedup 1.0000x reference)
//
#include <hip/hip_runtime.h>
#include <stdint.h>

#define NHEADS 16
#define HDIM   64
#define HID    1024
#define SEQ    2048
#define NB     2

typedef short s16x8 __attribute__((ext_vector_type(8)));
typedef float f32x4 __attribute__((ext_vector_type(4)));

// fp32 -> bf16 bits, round-to-nearest-even
__device__ __forceinline__ short f2bf(float f) {
  union { float f; unsigned u; } x; x.f = f;
  unsigned r = (x.u + 0x7FFFu + ((x.u >> 16) & 1u)) >> 16;
  return (short)r;
}
// bf16 bits -> fp32
__device__ __forceinline__ float bf2f(unsigned short u) {
  union { unsigned u; float f; } x; x.u = ((unsigned)u) << 16;
  return x.f;
}

// async global->LDS, 16B per lane; LDS dest = wave base + lane*16, src per-lane
__device__ __forceinline__ void gload16(const void* g, void* l) {
  __builtin_amdgcn_global_load_lds(
      (const __attribute__((address_space(1))) unsigned int*)g,
      (__attribute__((address_space(3))) unsigned int*)l, 16, 0, 0);
}

// ---------------------------------------------------------------------------
// Projections: 3 GEMMs (z = 0:Q, 1:K, 2:V) in one launch for TLP.
// C = A @ Wt^T, A bf16 [4096][1024] (pre-cast), Wt bf16 [1024][1024].
// BM=64, BN=128, BK=64, 4 waves (2x2), 24KB LDS, (256,4).  [R4-verbatim]
// z<2: head layout [B][NH][SEQ][HDIM] (Q scaled 0.125); z=2: [B][NH][HDIM][SEQ].
__global__ __launch_bounds__(256, 4)
void proj_gemm(const unsigned short* __restrict__ qb, const unsigned short* __restrict__ kb,
               const unsigned short* __restrict__ vb,
               const unsigned short* __restrict__ wqt, const unsigned short* __restrict__ wkt,
               const unsigned short* __restrict__ wvt,
               unsigned short* __restrict__ Qh, unsigned short* __restrict__ Kh,
               unsigned short* __restrict__ Vt)
{
  __shared__ unsigned short As[64 * 64];
  __shared__ unsigned short Bs[128 * 64];
  const int tid = threadIdx.x, lane = tid & 63, w = tid >> 6;
  const int lg = lane >> 4, ll = lane & 15;
  const int wm = w & 1, wn = w >> 1;
  const int z = blockIdx.z;
  const int m0 = blockIdx.x * 64, n0 = blockIdx.y * 128;
  const int xorv = (ll & 7) << 4;

  const unsigned short* A  = z == 0 ? qb : z == 1 ? kb : vb;
  const unsigned short* Bt = z == 0 ? wqt : z == 1 ? wkt : wvt;
  const float alpha = z == 0 ? 0.125f : 1.0f;

  f32x4 acc[2][4];
#pragma unroll
  for (int m = 0; m < 2; ++m)
#pragma unroll
    for (int n = 0; n < 4; ++n) acc[m][n] = (f32x4)0.f;

  int rA[2], cA[2], rB[4], cB[4];
#pragma unroll
  for (int c = 0; c < 2; ++c) {
    const int b = (w * 2 + c) * 1024 + lane * 16;
    rA[c] = b >> 7; cA[c] = (b & 127) ^ ((rA[c] & 7) << 4);
  }
#pragma unroll
  for (int c = 0; c < 4; ++c) {
    const int b = (w * 4 + c) * 1024 + lane * 16;
    rB[c] = b >> 7; cB[c] = (b & 127) ^ ((rB[c] & 7) << 4);
  }

  for (int k0 = 0; k0 < HID; k0 += 64) {
    __syncthreads();
#pragma unroll
    for (int c = 0; c < 2; ++c)
      gload16((const char*)A + ((((size_t)(m0 + rA[c]) * HID + k0) << 1) + cA[c]),
              (char*)As + (w * 2 + c) * 1024);
#pragma unroll
    for (int c = 0; c < 4; ++c)
      gload16((const char*)Bt + ((((size_t)(n0 + rB[c]) * HID + k0) << 1) + cB[c]),
              (char*)Bs + (w * 4 + c) * 1024);
    __syncthreads();
#pragma unroll
    for (int kk = 0; kk < 2; ++kk) {
      const int cb2 = kk * 64 + lg * 16;
      s16x8 a[2], b[4];
#pragma unroll
      for (int m = 0; m < 2; ++m)
        a[m] = *(const s16x8*)((const char*)As + ((((wm * 32 + m * 16 + ll) << 7) + cb2) ^ xorv));
#pragma unroll
      for (int n = 0; n < 4; ++n)
        b[n] = *(const s16x8*)((const char*)Bs + ((((wn * 64 + n * 16 + ll) << 7) + cb2) ^ xorv));
#pragma unroll
      for (int m = 0; m < 2; ++m)
#pragma unroll
        for (int n = 0; n < 4; ++n)
          acc[m][n] = __builtin_amdgcn_mfma_f32_16x16x32_bf16(a[m], b[n], acc[m][n], 0, 0, 0);
    }
  }

#pragma unroll
  for (int m = 0; m < 2; ++m)
#pragma unroll
    for (int n = 0; n < 4; ++n)
#pragma unroll
      for (int r = 0; r < 4; ++r) {
        const int row = m0 + wm * 32 + m * 16 + lg * 4 + r;
        const int col = n0 + wn * 64 + n * 16 + ll;
        const int bb = row >> 11, l = row & (SEQ - 1);
        const int h = col >> 6, d = col & (HDIM - 1);
        const unsigned short o = (unsigned short)f2bf(acc[m][n][r] * alpha);
        if (z < 2) {
          unsigned short* out = z == 0 ? Qh : Kh;
          out[(((size_t)(bb * NHEADS + h) * SEQ + l) * HDIM) + d] = o;
        } else {
          Vt[(((size_t)(bb * NHEADS + h) * HDIM + d) * SEQ) + l] = o;
        }
      }
}

// FC GEMM: xres = Ofc @ wft^T + resid. BM=64, BN=128, 512 blocks. [R4-verbatim]
__global__ __launch_bounds__(256, 4)
void fc_gemm(const unsigned short* __restrict__ A, const unsigned short* __restrict__ Bt,
             float* __restrict__ C, const float* __restrict__ resid)
{
  __shared__ unsigned short As[64 * 64];
  __shared__ unsigned short Bs[128 * 64];
  const int tid = threadIdx.x, lane = tid & 63, w = tid >> 6;
  const int lg = lane >> 4, ll = lane & 15;
  const int wm = w & 1, wn = w >> 1;
  const int m0 = blockIdx.x * 64, n0 = blockIdx.y * 128;
  const int xorv = (ll & 7) << 4;

  f32x4 acc[2][4];
#pragma unroll
  for (int m = 0; m < 2; ++m)
#pragma unroll
    for (int n = 0; n < 4; ++n) acc[m][n] = (f32x4)0.f;

  int rA[2], cA[2], rB[4], cB[4];
#pragma unroll
  for (int c = 0; c < 2; ++c) {
    const int b = (w * 2 + c) * 1024 + lane * 16;
    rA[c] = b >> 7; cA[c] = (b & 127) ^ ((rA[c] & 7) << 4);
  }
#pragma unroll
  for (int c = 0; c < 4; ++c) {
    const int b = (w * 4 + c) * 1024 + lane * 16;
    rB[c] = b >> 7; cB[c] = (b & 127) ^ ((rB[c] & 7) << 4);
  }

  for (int k0 = 0; k0 < HID; k0 += 64) {
    __syncthreads();
#pragma unroll
    for (int c = 0; c < 2; ++c)
      gload16((const char*)A + ((((size_t)(m0 + rA[c]) * HID + k0) << 1) + cA[c]),
              (char*)As + (w * 2 + c) * 1024);
#pragma unroll
    for (int c = 0; c < 4; ++c)
      gload16((const char*)Bt + ((((size_t)(n0 + rB[c]) * HID + k0) << 1) + cB[c]),
              (char*)Bs + (w * 4 + c) * 1024);
    __syncthreads();
#pragma unroll
    for (int kk = 0; kk < 2; ++kk) {
      const int cb2 = kk * 64 + lg * 16;
      s16x8 a[2], b[4];
#pragma unroll
      for (int m = 0; m < 2; ++m)
        a[m] = *(const s16x8*)((const char*)As + ((((wm * 32 + m * 16 + ll) << 7) + cb2) ^ xorv));
#pragma unroll
      for (int n = 0; n < 4; ++n)
        b[n] = *(const s16x8*)((const char*)Bs + ((((wn * 64 + n * 16 + ll) << 7) + cb2) ^ xorv));
#pragma unroll
      for (int m = 0; m < 2; ++m)
#pragma unroll
        for (int n = 0; n < 4; ++n)
          acc[m][n] = __builtin_amdgcn_mfma_f32_16x16x32_bf16(a[m], b[n], acc[m][n], 0, 0, 0);
    }
  }

#pragma unroll
  for (int m = 0; m < 2; ++m)
#pragma unroll
    for (int n = 0; n < 4; ++n)
#pragma unroll
      for (int r = 0; r < 4; ++r) {
        const int row = m0 + wm * 32 + m * 16 + lg * 4 + r;
        const int col = n0 + wn * 64 + n * 16 + ll;
        const size_t idx = (size_t)row * HID + col;
        C[idx] = acc[m][n][r] + resid[idx];
      }
}

// ---------------------------------------------------------------------------
// Fused attention, 2-pass, sum-only softmax. [R4 base; ONE change: pass-2
// attn store vectorized — pack Ps(bf16) -> PV MFMA -> re-read Ps, 2x16B NT
// stores per slot (8x fewer store insts, 128B dense segments).]
__global__ __launch_bounds__(256, 3)
void fused_attn(const unsigned short* __restrict__ Qh,
                const unsigned short* __restrict__ Kh,
                const unsigned short* __restrict__ Vt,
                float* __restrict__ attn,
                unsigned short* __restrict__ Ofc)
{
  __shared__ unsigned short Ks[128 * 64];   // 16KB, swizzled
  __shared__ unsigned short Vs[64 * 128];   // 16KB, swizzled (256B rows)
  __shared__ unsigned short Ps[128][72];    // 18KB, 64-key half-chunk
  const int tid = threadIdx.x, lane = tid & 63, w = tid >> 6;
  const int lg = lane >> 4, ll = lane & 15;
  const int xorv = (ll & 7) << 4;

  // bijective XCD remap: each XCD owns 4 heads (K/V L2-resident)
  const int lin = blockIdx.y * gridDim.x + blockIdx.x;
  const int lin2 = (lin & 7) * 64 + (lin >> 3);
  const int z = lin2 >> 4, qb = lin2 & 15;
  const int bb = z >> 4, h = z & 15;
  const int m0 = qb * 128;

  const unsigned short* Qz = Qh + (size_t)z * SEQ * HDIM;
  const unsigned short* Kz = Kh + (size_t)z * SEQ * HDIM;
  const unsigned short* Vz = Vt + (size_t)z * HDIM * SEQ;
  float* Az = attn + (size_t)z * SEQ * SEQ;

  int rK[4], cbK[4], rV[4], cbV[4];
#pragma unroll
  for (int c = 0; c < 4; ++c) {
    const int b = (w * 4 + c) * 1024 + lane * 16;
    rK[c] = b >> 7; cbK[c] = (b & 127) ^ ((rK[c] & 7) << 4);
    rV[c] = b >> 8; cbV[c] = (b & 255) ^ ((rV[c] & 7) << 4);
  }

  // Q fragments (held all kernel)
  s16x8 qf[2][2];
#pragma unroll
  for (int m = 0; m < 2; ++m)
#pragma unroll
    for (int kk = 0; kk < 2; ++kk)
      qf[m][kk] = *(const s16x8*)(Qz + (size_t)(m0 + w * 32 + m * 16 + ll) * HDIM
                                  + kk * 32 + lg * 8);

  float sml[8];
#pragma unroll
  for (int i = 0; i < 8; ++i) sml[i] = 0.f;

  // ---------------- pass 1: per-lane exp-sum ----------------
  for (int j = 0; j < 16; ++j) {
    __syncthreads();
#pragma unroll
    for (int c = 0; c < 4; ++c)
      gload16((const char*)Kz + ((((size_t)(j * 128 + rK[c]) * HDIM) << 1) + cbK[c]),
              (char*)Ks + (w * 4 + c) * 1024);
    __syncthreads();
    f32x4 s[2][8];
#pragma unroll
    for (int m = 0; m < 2; ++m)
#pragma unroll
      for (int n = 0; n < 8; ++n) s[m][n] = (f32x4)0.f;
#pragma unroll
    for (int kk = 0; kk < 2; ++kk) {
      const int cb2 = kk * 64 + lg * 16;
      s16x8 bk[8];
#pragma unroll
      for (int n = 0; n < 8; ++n)
        bk[n] = *(const s16x8*)((const char*)Ks + ((((n * 16 + ll) << 7) + cb2) ^ xorv));
#pragma unroll
      for (int m = 0; m < 2; ++m)
#pragma unroll
        for (int n = 0; n < 8; ++n)
          s[m][n] = __builtin_amdgcn_mfma_f32_16x16x32_bf16(qf[m][kk], bk[n], s[m][n], 0, 0, 0);
    }
#pragma unroll
    for (int m = 0; m < 2; ++m)
#pragma unroll
      for (int r = 0; r < 4; ++r) {
        const int i = m * 4 + r;
#pragma unroll
        for (int n = 0; n < 8; ++n) sml[i] += __expf(s[m][n][r]);
      }
  }
  float inv[8];
#pragma unroll
  for (int i = 0; i < 8; ++i) {
    float su = sml[i];
#pragma unroll
    for (int off = 1; off < 16; off <<= 1) su += __shfl_xor(su, off, 64);
    inv[i] = 1.0f / su;
  }

  f32x4 ao[2][4];
#pragma unroll
  for (int m = 0; m < 2; ++m)
#pragma unroll
    for (int n = 0; n < 4; ++n) ao[m][n] = (f32x4)0.f;

  // ---------------- pass 2: recompute, pack Ps, P@V, vector attn store ----------------
  for (int j = 0; j < 16; ++j) {
    __syncthreads();
#pragma unroll
    for (int c = 0; c < 4; ++c) {
      gload16((const char*)Kz + ((((size_t)(j * 128 + rK[c]) * HDIM) << 1) + cbK[c]),
              (char*)Ks + (w * 4 + c) * 1024);
      gload16((const char*)Vz + ((((size_t)rV[c] * SEQ + j * 128) << 1) + cbV[c]),
              (char*)Vs + (w * 4 + c) * 1024);
    }
    __syncthreads();
    f32x4 s[2][8];
#pragma unroll
    for (int m = 0; m < 2; ++m)
#pragma unroll
      for (int n = 0; n < 8; ++n) s[m][n] = (f32x4)0.f;
#pragma unroll
    for (int kk = 0; kk < 2; ++kk) {
      const int cb2 = kk * 64 + lg * 16;
      s16x8 bk[8];
#pragma unroll
      for (int n = 0; n < 8; ++n)
        bk[n] = *(const s16x8*)((const char*)Ks + ((((n * 16 + ll) << 7) + cb2) ^ xorv));
#pragma unroll
      for (int m = 0; m < 2; ++m)
#pragma unroll
        for (int n = 0; n < 8; ++n)
          s[m][n] = __builtin_amdgcn_mfma_f32_16x16x32_bf16(qf[m][kk], bk[n], s[m][n], 0, 0, 0);
    }
    // two 64-key halves: pack normalized P (bf16) -> PV MFMA -> vector NT store
#pragma unroll
    for (int h2 = 0; h2 < 2; ++h2) {
#pragma unroll
      for (int m = 0; m < 2; ++m)
#pragma unroll
        for (int r = 0; r < 4; ++r) {
          const int i = m * 4 + r;
          const int rowl = w * 32 + m * 16 + lg * 4 + r;
#pragma unroll
          for (int nn = 0; nn < 4; ++nn)
            Ps[rowl][nn * 16 + ll] =
                (unsigned short)f2bf(__expf(s[m][h2 * 4 + nn][r]) * inv[i]);
        }
      // PV on this half (wave-private Ps rows; no barrier needed)
#pragma unroll
      for (int kkl = 0; kkl < 2; ++kkl) {
        const int cb2v = (h2 * 2 + kkl) * 64 + lg * 16;
        s16x8 pa[2], vbf[4];
#pragma unroll
        for (int m = 0; m < 2; ++m)
          pa[m] = *(const s16x8*)&Ps[w * 32 + m * 16 + ll][kkl * 32 + lg * 8];
#pragma unroll
        for (int n = 0; n < 4; ++n)
          vbf[n] = *(const s16x8*)((const char*)Vs + ((((n * 16 + ll) << 8) + cb2v) ^ xorv));
#pragma unroll
        for (int m = 0; m < 2; ++m)
#pragma unroll
          for (int n = 0; n < 4; ++n)
            ao[m][n] = __builtin_amdgcn_mfma_f32_16x16x32_bf16(pa[m], vbf[n], ao[m][n], 0, 0, 0);
      }
      // vector attn store: wave's 32 rows x 64 keys; 32B/lane, 128B segments
#pragma unroll
      for (int vv = 0; vv < 4; ++vv) {
        const int slot = vv * 64 + lane;
        const int srow = slot >> 3, k8 = slot & 7;
        const s16x8 pw = *(const s16x8*)&Ps[w * 32 + srow][k8 * 8];
        f32x4 o0, o1;
        o0[0] = bf2f((unsigned short)pw[0]); o0[1] = bf2f((unsigned short)pw[1]);
        o0[2] = bf2f((unsigned short)pw[2]); o0[3] = bf2f((unsigned short)pw[3]);
        o1[0] = bf2f((unsigned short)pw[4]); o1[1] = bf2f((unsigned short)pw[5]);
        o1[2] = bf2f((unsigned short)pw[6]); o1[3] = bf2f((unsigned short)pw[7]);
        f32x4* dst = (f32x4*)(Az + (size_t)(m0 + w * 32 + srow) * SEQ
                              + j * 128 + h2 * 64 + k8 * 8);
        __builtin_nontemporal_store(o0, dst);
        __builtin_nontemporal_store(o1, dst + 1);
      }
    }
  }

#pragma unroll
  for (int m = 0; m < 2; ++m)
#pragma unroll
    for (int n = 0; n < 4; ++n)
#pragma unroll
      for (int r = 0; r < 4; ++r) {
        const int qrow = m0 + w * 32 + m * 16 + lg * 4 + r;
        const int d = n * 16 + ll;
        Ofc[((size_t)bb * SEQ + qrow) * HID + h * HDIM + d] =
            (unsigned short)f2bf(ao[m][n][r]);
      }
}

// ---------------------------------------------------------------------------
// cast q,k,v fp32 -> bf16 (8 elems/thread), grid.y selects input
__global__ __launch_bounds__(256)
void cast3_bf16(const float* __restrict__ s0, const float* __restrict__ s1,
                const float* __restrict__ s2, unsigned short* __restrict__ d0,
                unsigned short* __restrict__ d1, unsigned short* __restrict__ d2)
{
  const float* s = blockIdx.y == 0 ? s0 : blockIdx.y == 1 ? s1 : s2;
  unsigned short* d = blockIdx.y == 0 ? d0 : blockIdx.y == 1 ? d1 : d2;
  const size_t i = ((size_t)blockIdx.x * 256 + threadIdx.x) * 8;
  const float4 f0 = ((const float4*)(s + i))[0];
  const float4 f1 = ((const float4*)(s + i))[1];
  s16x8 o;
  o[0] = f2bf(f0.x); o[1] = f2bf(f0.y); o[2] = f2bf(f0.z); o[3] = f2bf(f0.w);
  o[4] = f2bf(f1.x); o[5] = f2bf(f1.y); o[6] = f2bf(f1.z); o[7] = f2bf(f1.w);
  *(s16x8*)(d + i) = o;
}

__global__ __launch_bounds__(256)
void transpose_cast_w4(const float* __restrict__ s0, const float* __restrict__ s1,
                       const float* __restrict__ s2, const float* __restrict__ s3,
                       unsigned short* __restrict__ d0, unsigned short* __restrict__ d1,
                       unsigned short* __restrict__ d2, unsigned short* __restrict__ d3)
{
  const float* src = blockIdx.z == 0 ? s0 : blockIdx.z == 1 ? s1 : blockIdx.z == 2 ? s2 : s3;
  unsigned short* dst = blockIdx.z == 0 ? d0 : blockIdx.z == 1 ? d1 : blockIdx.z == 2 ? d2 : d3;
  __shared__ float t[32][33];
  const int tx = threadIdx.x & 31, ty = threadIdx.x >> 5;
  const int x0 = blockIdx.x * 32, y0 = blockIdx.y * 32;
#pragma unroll
  for (int i = 0; i < 4; ++i) {
    const int r = ty + i * 8;
    t[r][tx] = src[(size_t)(y0 + r) * HID + (x0 + tx)];
  }
  __syncthreads();
#pragma unroll
  for (int i = 0; i < 4; ++i) {
    const int r = ty + i * 8;
    dst[(size_t)(x0 + r) * HID + (y0 + tx)] = (unsigned short)f2bf(t[tx][r]);
  }
}

__global__ __launch_bounds__(256)
void ln_kernel(const float* __restrict__ x, const float* __restrict__ gamma,
               const float* __restrict__ beta, float* __restrict__ y)
{
  const int tid = threadIdx.x;
  const size_t row = blockIdx.x;
  const float4 v = ((const float4*)(x + row * HID))[tid];
  float s = v.x + v.y + v.z + v.w;
  float q = v.x * v.x + v.y * v.y + v.z * v.z + v.w * v.w;
#pragma unroll
  for (int off = 32; off; off >>= 1) {
    s += __shfl_xor(s, off, 64);
    q += __shfl_xor(q, off, 64);
  }
  __shared__ float ps[4], pq[4];
  const int wid = tid >> 6, lane = tid & 63;
  if (lane == 0) { ps[wid] = s; pq[wid] = q; }
  __syncthreads();
  const float ts = ps[0] + ps[1] + ps[2] + ps[3];
  const float tq = pq[0] + pq[1] + pq[2] + pq[3];
  const float mu = ts * (1.0f / HID);
  const float var = tq * (1.0f / HID) - mu * mu;
  const float rs = rsqrtf(var + 1e-6f);
  const float4 g = ((const float4*)gamma)[tid];
  const float4 bb = ((const float4*)beta)[tid];
  float4 o;
  o.x = (v.x - mu) * rs * g.x + bb.x;
  o.y = (v.y - mu) * rs * g.y + bb.y;
  o.z = (v.z - mu) * rs * g.z + bb.z;
  o.w = (v.w - mu) * rs * g.w + bb.w;
  ((float4*)(y + row * HID))[tid] = o;
}

extern "C" void kernel_launch(void* const* d_in, const int* in_sizes, int n_in,
                              void* d_out, int out_size, void* d_ws, size_t ws_size,
                              hipStream_t stream)
{
  (void)in_sizes; (void)n_in; (void)out_size; (void)ws_size;
  const float* q     = (const float*)d_in[0];
  const float* k     = (const float*)d_in[1];
  const float* v     = (const float*)d_in[2];
  const float* w_qs  = (const float*)d_in[3];
  const float* w_ks  = (const float*)d_in[4];
  const float* w_vs  = (const float*)d_in[5];
  const float* w_fc  = (const float*)d_in[6];
  const float* gamma = (const float*)d_in[7];
  const float* beta  = (const float*)d_in[8];

  char* ws = (char*)d_ws;
  unsigned short* wqt = (unsigned short*)(ws);                      // 4 x 2 MB
  unsigned short* wkt = (unsigned short*)(ws + ((size_t)2 << 20));
  unsigned short* wvt = (unsigned short*)(ws + ((size_t)4 << 20));
  unsigned short* wft = (unsigned short*)(ws + ((size_t)6 << 20));
  unsigned short* qb  = (unsigned short*)(ws + ((size_t)8 << 20));  // 8 MB each
  unsigned short* kb  = (unsigned short*)(ws + ((size_t)16 << 20));
  unsigned short* vb  = (unsigned short*)(ws + ((size_t)24 << 20));
  unsigned short* Qh  = (unsigned short*)(ws + ((size_t)32 << 20));
  unsigned short* Kh  = (unsigned short*)(ws + ((size_t)40 << 20));
  unsigned short* Vt  = (unsigned short*)(ws + ((size_t)48 << 20));
  unsigned short* Ofc = qb;                                         // reuse (dead)
  float*          xres = (float*)(ws + ((size_t)16 << 20));         // reuse kb+vb

  float* y_out = (float*)d_out;
  float* attn  = (float*)d_out + (size_t)NB * SEQ * HID;

  const dim3 b256(256, 1, 1);

  transpose_cast_w4<<<dim3(32, 32, 4), b256, 0, stream>>>(
      w_qs, w_ks, w_vs, w_fc, wqt, wkt, wvt, wft);
  cast3_bf16<<<dim3(2048, 3, 1), b256, 0, stream>>>(q, k, v, qb, kb, vb);

  proj_gemm<<<dim3(64, 8, 3), b256, 0, stream>>>(qb, kb, vb, wqt, wkt, wvt, Qh, Kh, Vt);

  fused_attn<<<dim3(16, 32, 1), b256, 0, stream>>>(Qh, Kh, Vt, attn, Ofc);

  fc_gemm<<<dim3(64, 8, 1), b256, 0, stream>>>(Ofc, wft, xres, q);

  ln_kernel<<<dim3(NB * SEQ, 1, 1), b256, 0, stream>>>(xres, gamma, beta, y_out);
}

// Round 9
// 255.456 us; speedup vs baseline: 1.5217x; 1.5217x over previous
//
#include <hip/hip_runtime.h>
#include <stdint.h>

#define NHEADS 16
#define HDIM   64
#define HID    1024
#define SEQ    2048
#define NB     2

typedef short s16x8 __attribute__((ext_vector_type(8)));
typedef float f32x4 __attribute__((ext_vector_type(4)));

// fp32 -> bf16 bits, round-to-nearest-even
__device__ __forceinline__ short f2bf(float f) {
  union { float f; unsigned u; } x; x.f = f;
  unsigned r = (x.u + 0x7FFFu + ((x.u >> 16) & 1u)) >> 16;
  return (short)r;
}

// async global->LDS, 16B per lane; LDS dest = wave base + lane*16, src per-lane
__device__ __forceinline__ void gload16(const void* g, void* l) {
  __builtin_amdgcn_global_load_lds(
      (const __attribute__((address_space(1))) unsigned int*)g,
      (__attribute__((address_space(3))) unsigned int*)l, 16, 0, 0);
}

// ---------------------------------------------------------------------------
// Fused prep: z in [0,4) -> transpose+cast weight z (32x32 LDS tiles, bx
// decomposed to (x0,y0)); z in [4,7) -> cast input z-4 to bf16 (4096 f/block).
__global__ __launch_bounds__(256)
void prep(const float* __restrict__ w0, const float* __restrict__ w1,
          const float* __restrict__ w2, const float* __restrict__ w3,
          const float* __restrict__ q, const float* __restrict__ k,
          const float* __restrict__ v,
          unsigned short* __restrict__ d0, unsigned short* __restrict__ d1,
          unsigned short* __restrict__ d2, unsigned short* __restrict__ d3,
          unsigned short* __restrict__ qb, unsigned short* __restrict__ kb,
          unsigned short* __restrict__ vb)
{
  const int z = blockIdx.z;
  if (z < 4) {
    const float* src = z == 0 ? w0 : z == 1 ? w1 : z == 2 ? w2 : w3;
    unsigned short* dst = z == 0 ? d0 : z == 1 ? d1 : z == 2 ? d2 : d3;
    __shared__ float t[32][33];
    const int tx = threadIdx.x & 31, ty = threadIdx.x >> 5;
    const int x0 = (blockIdx.x & 31) * 32, y0 = (blockIdx.x >> 5) * 32;
#pragma unroll
    for (int i = 0; i < 4; ++i) {
      const int r = ty + i * 8;
      t[r][tx] = src[(size_t)(y0 + r) * HID + (x0 + tx)];
    }
    __syncthreads();
#pragma unroll
    for (int i = 0; i < 4; ++i) {
      const int r = ty + i * 8;
      dst[(size_t)(x0 + r) * HID + (y0 + tx)] = (unsigned short)f2bf(t[tx][r]);
    }
  } else {
    const float* s = z == 4 ? q : z == 5 ? k : v;
    unsigned short* d = z == 4 ? qb : z == 5 ? kb : vb;
#pragma unroll
    for (int c = 0; c < 2; ++c) {
      const size_t i = (size_t)blockIdx.x * 4096 + c * 2048 + threadIdx.x * 8;
      const float4 f0 = ((const float4*)(s + i))[0];
      const float4 f1 = ((const float4*)(s + i))[1];
      s16x8 o;
      o[0] = f2bf(f0.x); o[1] = f2bf(f0.y); o[2] = f2bf(f0.z); o[3] = f2bf(f0.w);
      o[4] = f2bf(f1.x); o[5] = f2bf(f1.y); o[6] = f2bf(f1.z); o[7] = f2bf(f1.w);
      *(s16x8*)(d + i) = o;
    }
  }
}

// ---------------------------------------------------------------------------
// Projections: 3 GEMMs (z = 0:Q, 1:K, 2:V) in one launch for TLP.
// C = A @ Wt^T, A bf16 [4096][1024] (pre-cast), Wt bf16 [1024][1024].
// BM=64, BN=128, BK=64, 4 waves (2x2), 24KB LDS, (256,4).  [R4-verbatim]
// z<2: head layout [B][NH][SEQ][HDIM] (Q scaled 0.125); z=2: [B][NH][HDIM][SEQ].
__global__ __launch_bounds__(256, 4)
void proj_gemm(const unsigned short* __restrict__ qb, const unsigned short* __restrict__ kb,
               const unsigned short* __restrict__ vb,
               const unsigned short* __restrict__ wqt, const unsigned short* __restrict__ wkt,
               const unsigned short* __restrict__ wvt,
               unsigned short* __restrict__ Qh, unsigned short* __restrict__ Kh,
               unsigned short* __restrict__ Vt)
{
  __shared__ unsigned short As[64 * 64];
  __shared__ unsigned short Bs[128 * 64];
  const int tid = threadIdx.x, lane = tid & 63, w = tid >> 6;
  const int lg = lane >> 4, ll = lane & 15;
  const int wm = w & 1, wn = w >> 1;
  const int z = blockIdx.z;
  const int m0 = blockIdx.x * 64, n0 = blockIdx.y * 128;
  const int xorv = (ll & 7) << 4;

  const unsigned short* A  = z == 0 ? qb : z == 1 ? kb : vb;
  const unsigned short* Bt = z == 0 ? wqt : z == 1 ? wkt : wvt;
  const float alpha = z == 0 ? 0.125f : 1.0f;

  f32x4 acc[2][4];
#pragma unroll
  for (int m = 0; m < 2; ++m)
#pragma unroll
    for (int n = 0; n < 4; ++n) acc[m][n] = (f32x4)0.f;

  int rA[2], cA[2], rB[4], cB[4];
#pragma unroll
  for (int c = 0; c < 2; ++c) {
    const int b = (w * 2 + c) * 1024 + lane * 16;
    rA[c] = b >> 7; cA[c] = (b & 127) ^ ((rA[c] & 7) << 4);
  }
#pragma unroll
  for (int c = 0; c < 4; ++c) {
    const int b = (w * 4 + c) * 1024 + lane * 16;
    rB[c] = b >> 7; cB[c] = (b & 127) ^ ((rB[c] & 7) << 4);
  }

  for (int k0 = 0; k0 < HID; k0 += 64) {
    __syncthreads();
#pragma unroll
    for (int c = 0; c < 2; ++c)
      gload16((const char*)A + ((((size_t)(m0 + rA[c]) * HID + k0) << 1) + cA[c]),
              (char*)As + (w * 2 + c) * 1024);
#pragma unroll
    for (int c = 0; c < 4; ++c)
      gload16((const char*)Bt + ((((size_t)(n0 + rB[c]) * HID + k0) << 1) + cB[c]),
              (char*)Bs + (w * 4 + c) * 1024);
    __syncthreads();
#pragma unroll
    for (int kk = 0; kk < 2; ++kk) {
      const int cb2 = kk * 64 + lg * 16;
      s16x8 a[2], b[4];
#pragma unroll
      for (int m = 0; m < 2; ++m)
        a[m] = *(const s16x8*)((const char*)As + ((((wm * 32 + m * 16 + ll) << 7) + cb2) ^ xorv));
#pragma unroll
      for (int n = 0; n < 4; ++n)
        b[n] = *(const s16x8*)((const char*)Bs + ((((wn * 64 + n * 16 + ll) << 7) + cb2) ^ xorv));
#pragma unroll
      for (int m = 0; m < 2; ++m)
#pragma unroll
        for (int n = 0; n < 4; ++n)
          acc[m][n] = __builtin_amdgcn_mfma_f32_16x16x32_bf16(a[m], b[n], acc[m][n], 0, 0, 0);
    }
  }

#pragma unroll
  for (int m = 0; m < 2; ++m)
#pragma unroll
    for (int n = 0; n < 4; ++n)
#pragma unroll
      for (int r = 0; r < 4; ++r) {
        const int row = m0 + wm * 32 + m * 16 + lg * 4 + r;
        const int col = n0 + wn * 64 + n * 16 + ll;
        const int bb = row >> 11, l = row & (SEQ - 1);
        const int h = col >> 6, d = col & (HDIM - 1);
        const unsigned short o = (unsigned short)f2bf(acc[m][n][r] * alpha);
        if (z < 2) {
          unsigned short* out = z == 0 ? Qh : Kh;
          out[(((size_t)(bb * NHEADS + h) * SEQ + l) * HDIM) + d] = o;
        } else {
          Vt[(((size_t)(bb * NHEADS + h) * HDIM + d) * SEQ) + l] = o;
        }
      }
}

// FC GEMM: xres = Ofc @ wft^T + resid. BM=64, BN=128, 512 blocks. [R4-verbatim]
__global__ __launch_bounds__(256, 4)
void fc_gemm(const unsigned short* __restrict__ A, const unsigned short* __restrict__ Bt,
             float* __restrict__ C, const float* __restrict__ resid)
{
  __shared__ unsigned short As[64 * 64];
  __shared__ unsigned short Bs[128 * 64];
  const int tid = threadIdx.x, lane = tid & 63, w = tid >> 6;
  const int lg = lane >> 4, ll = lane & 15;
  const int wm = w & 1, wn = w >> 1;
  const int m0 = blockIdx.x * 64, n0 = blockIdx.y * 128;
  const int xorv = (ll & 7) << 4;

  f32x4 acc[2][4];
#pragma unroll
  for (int m = 0; m < 2; ++m)
#pragma unroll
    for (int n = 0; n < 4; ++n) acc[m][n] = (f32x4)0.f;

  int rA[2], cA[2], rB[4], cB[4];
#pragma unroll
  for (int c = 0; c < 2; ++c) {
    const int b = (w * 2 + c) * 1024 + lane * 16;
    rA[c] = b >> 7; cA[c] = (b & 127) ^ ((rA[c] & 7) << 4);
  }
#pragma unroll
  for (int c = 0; c < 4; ++c) {
    const int b = (w * 4 + c) * 1024 + lane * 16;
    rB[c] = b >> 7; cB[c] = (b & 127) ^ ((rB[c] & 7) << 4);
  }

  for (int k0 = 0; k0 < HID; k0 += 64) {
    __syncthreads();
#pragma unroll
    for (int c = 0; c < 2; ++c)
      gload16((const char*)A + ((((size_t)(m0 + rA[c]) * HID + k0) << 1) + cA[c]),
              (char*)As + (w * 2 + c) * 1024);
#pragma unroll
    for (int c = 0; c < 4; ++c)
      gload16((const char*)Bt + ((((size_t)(n0 + rB[c]) * HID + k0) << 1) + cB[c]),
              (char*)Bs + (w * 4 + c) * 1024);
    __syncthreads();
#pragma unroll
    for (int kk = 0; kk < 2; ++kk) {
      const int cb2 = kk * 64 + lg * 16;
      s16x8 a[2], b[4];
#pragma unroll
      for (int m = 0; m < 2; ++m)
        a[m] = *(const s16x8*)((const char*)As + ((((wm * 32 + m * 16 + ll) << 7) + cb2) ^ xorv));
#pragma unroll
      for (int n = 0; n < 4; ++n)
        b[n] = *(const s16x8*)((const char*)Bs + ((((wn * 64 + n * 16 + ll) << 7) + cb2) ^ xorv));
#pragma unroll
      for (int m = 0; m < 2; ++m)
#pragma unroll
        for (int n = 0; n < 4; ++n)
          acc[m][n] = __builtin_amdgcn_mfma_f32_16x16x32_bf16(a[m], b[n], acc[m][n], 0, 0, 0);
    }
  }

#pragma unroll
  for (int m = 0; m < 2; ++m)
#pragma unroll
    for (int n = 0; n < 4; ++n)
#pragma unroll
      for (int r = 0; r < 4; ++r) {
        const int row = m0 + wm * 32 + m * 16 + lg * 4 + r;
        const int col = n0 + wn * 64 + n * 16 + ll;
        const size_t idx = (size_t)row * HID + col;
        C[idx] = acc[m][n][r] + resid[idx];
      }
}

// ---------------------------------------------------------------------------
// Fused attention, 2-pass, sum-only softmax (S ~ N(0,1) by construction,
// exp(s) fp32-safe; math identical to reference's max-shifted softmax).
// Pass 1: QK^T, per-lane exp-sum. Pass 2: recompute, P = exp(s)*inv,
// scalar nontemporal attn store (once), O += P@V via half-chunk wave-private
// Ps. LDS 50KB -> 3 blocks/CU.  [R4-verbatim: known-good 256us config.
// DO NOT add register pressure here: (256,3) is at the VGPR cliff — both
// R5/R8 epilogue experiments (+16 live VGPRs) spilled and cost +130us.]
__global__ __launch_bounds__(256, 3)
void fused_attn(const unsigned short* __restrict__ Qh,
                const unsigned short* __restrict__ Kh,
                const unsigned short* __restrict__ Vt,
                float* __restrict__ attn,
                unsigned short* __restrict__ Ofc)
{
  __shared__ unsigned short Ks[128 * 64];   // 16KB, swizzled
  __shared__ unsigned short Vs[64 * 128];   // 16KB, swizzled (256B rows)
  __shared__ unsigned short Ps[128][72];    // 18KB, 64-key half-chunk
  const int tid = threadIdx.x, lane = tid & 63, w = tid >> 6;
  const int lg = lane >> 4, ll = lane & 15;
  const int xorv = (ll & 7) << 4;

  // bijective XCD remap: each XCD owns 4 heads (K/V L2-resident)
  const int lin = blockIdx.y * gridDim.x + blockIdx.x;
  const int lin2 = (lin & 7) * 64 + (lin >> 3);
  const int z = lin2 >> 4, qb = lin2 & 15;
  const int bb = z >> 4, h = z & 15;
  const int m0 = qb * 128;

  const unsigned short* Qz = Qh + (size_t)z * SEQ * HDIM;
  const unsigned short* Kz = Kh + (size_t)z * SEQ * HDIM;
  const unsigned short* Vz = Vt + (size_t)z * HDIM * SEQ;
  float* Az = attn + (size_t)z * SEQ * SEQ;

  int rK[4], cbK[4], rV[4], cbV[4];
#pragma unroll
  for (int c = 0; c < 4; ++c) {
    const int b = (w * 4 + c) * 1024 + lane * 16;
    rK[c] = b >> 7; cbK[c] = (b & 127) ^ ((rK[c] & 7) << 4);
    rV[c] = b >> 8; cbV[c] = (b & 255) ^ ((rV[c] & 7) << 4);
  }

  // Q fragments (held all kernel)
  s16x8 qf[2][2];
#pragma unroll
  for (int m = 0; m < 2; ++m)
#pragma unroll
    for (int kk = 0; kk < 2; ++kk)
      qf[m][kk] = *(const s16x8*)(Qz + (size_t)(m0 + w * 32 + m * 16 + ll) * HDIM
                                  + kk * 32 + lg * 8);

  float sml[8];
#pragma unroll
  for (int i = 0; i < 8; ++i) sml[i] = 0.f;

  // ---------------- pass 1: per-lane exp-sum ----------------
  for (int j = 0; j < 16; ++j) {
    __syncthreads();
#pragma unroll
    for (int c = 0; c < 4; ++c)
      gload16((const char*)Kz + ((((size_t)(j * 128 + rK[c]) * HDIM) << 1) + cbK[c]),
              (char*)Ks + (w * 4 + c) * 1024);
    __syncthreads();
    f32x4 s[2][8];
#pragma unroll
    for (int m = 0; m < 2; ++m)
#pragma unroll
      for (int n = 0; n < 8; ++n) s[m][n] = (f32x4)0.f;
#pragma unroll
    for (int kk = 0; kk < 2; ++kk) {
      const int cb2 = kk * 64 + lg * 16;
      s16x8 bk[8];
#pragma unroll
      for (int n = 0; n < 8; ++n)
        bk[n] = *(const s16x8*)((const char*)Ks + ((((n * 16 + ll) << 7) + cb2) ^ xorv));
#pragma unroll
      for (int m = 0; m < 2; ++m)
#pragma unroll
        for (int n = 0; n < 8; ++n)
          s[m][n] = __builtin_amdgcn_mfma_f32_16x16x32_bf16(qf[m][kk], bk[n], s[m][n], 0, 0, 0);
    }
#pragma unroll
    for (int m = 0; m < 2; ++m)
#pragma unroll
      for (int r = 0; r < 4; ++r) {
        const int i = m * 4 + r;
#pragma unroll
        for (int n = 0; n < 8; ++n) sml[i] += __expf(s[m][n][r]);
      }
  }
  float inv[8];
#pragma unroll
  for (int i = 0; i < 8; ++i) {
    float su = sml[i];
#pragma unroll
    for (int off = 1; off < 16; off <<= 1) su += __shfl_xor(su, off, 64);
    inv[i] = 1.0f / su;
  }

  f32x4 ao[2][4];
#pragma unroll
  for (int m = 0; m < 2; ++m)
#pragma unroll
    for (int n = 0; n < 4; ++n) ao[m][n] = (f32x4)0.f;

  // ---------------- pass 2: recompute, pack Ps, P@V, nt attn store ----------------
  for (int j = 0; j < 16; ++j) {
    __syncthreads();
#pragma unroll
    for (int c = 0; c < 4; ++c) {
      gload16((const char*)Kz + ((((size_t)(j * 128 + rK[c]) * HDIM) << 1) + cbK[c]),
              (char*)Ks + (w * 4 + c) * 1024);
      gload16((const char*)Vz + ((((size_t)rV[c] * SEQ + j * 128) << 1) + cbV[c]),
              (char*)Vs + (w * 4 + c) * 1024);
    }
    __syncthreads();
    f32x4 s[2][8];
#pragma unroll
    for (int m = 0; m < 2; ++m)
#pragma unroll
      for (int n = 0; n < 8; ++n) s[m][n] = (f32x4)0.f;
#pragma unroll
    for (int kk = 0; kk < 2; ++kk) {
      const int cb2 = kk * 64 + lg * 16;
      s16x8 bk[8];
#pragma unroll
      for (int n = 0; n < 8; ++n)
        bk[n] = *(const s16x8*)((const char*)Ks + ((((n * 16 + ll) << 7) + cb2) ^ xorv));
#pragma unroll
      for (int m = 0; m < 2; ++m)
#pragma unroll
        for (int n = 0; n < 8; ++n)
          s[m][n] = __builtin_amdgcn_mfma_f32_16x16x32_bf16(qf[m][kk], bk[n], s[m][n], 0, 0, 0);
    }
    // two 64-key halves: pack normalized P (bf16) + scalar nt store -> PV MFMA
#pragma unroll
    for (int h2 = 0; h2 < 2; ++h2) {
#pragma unroll
      for (int m = 0; m < 2; ++m)
#pragma unroll
        for (int r = 0; r < 4; ++r) {
          const int i = m * 4 + r;
          const int rowl = w * 32 + m * 16 + lg * 4 + r;
          float* dst = Az + (size_t)(m0 + rowl) * SEQ + j * 128 + h2 * 64 + ll;
#pragma unroll
          for (int nn = 0; nn < 4; ++nn) {
            const float p = __expf(s[m][h2 * 4 + nn][r]) * inv[i];
            __builtin_nontemporal_store(p, dst + nn * 16);
            Ps[rowl][nn * 16 + ll] = (unsigned short)f2bf(p);
          }
        }
      // PV on this half (wave-private Ps rows; no barrier needed)
#pragma unroll
      for (int kkl = 0; kkl < 2; ++kkl) {
        const int cb2v = (h2 * 2 + kkl) * 64 + lg * 16;
        s16x8 pa[2], vbf[4];
#pragma unroll
        for (int m = 0; m < 2; ++m)
          pa[m] = *(const s16x8*)&Ps[w * 32 + m * 16 + ll][kkl * 32 + lg * 8];
#pragma unroll
        for (int n = 0; n < 4; ++n)
          vbf[n] = *(const s16x8*)((const char*)Vs + ((((n * 16 + ll) << 8) + cb2v) ^ xorv));
#pragma unroll
        for (int m = 0; m < 2; ++m)
#pragma unroll
          for (int n = 0; n < 4; ++n)
            ao[m][n] = __builtin_amdgcn_mfma_f32_16x16x32_bf16(pa[m], vbf[n], ao[m][n], 0, 0, 0);
      }
    }
  }

#pragma unroll
  for (int m = 0; m < 2; ++m)
#pragma unroll
    for (int n = 0; n < 4; ++n)
#pragma unroll
      for (int r = 0; r < 4; ++r) {
        const int qrow = m0 + w * 32 + m * 16 + lg * 4 + r;
        const int d = n * 16 + ll;
        Ofc[((size_t)bb * SEQ + qrow) * HID + h * HDIM + d] =
            (unsigned short)f2bf(ao[m][n][r]);
      }
}

// ---------------------------------------------------------------------------
__global__ __launch_bounds__(256)
void ln_kernel(const float* __restrict__ x, const float* __restrict__ gamma,
               const float* __restrict__ beta, float* __restrict__ y)
{
  const int tid = threadIdx.x;
  const size_t row = blockIdx.x;
  const float4 v = ((const float4*)(x + row * HID))[tid];
  float s = v.x + v.y + v.z + v.w;
  float q = v.x * v.x + v.y * v.y + v.z * v.z + v.w * v.w;
#pragma unroll
  for (int off = 32; off; off >>= 1) {
    s += __shfl_xor(s, off, 64);
    q += __shfl_xor(q, off, 64);
  }
  __shared__ float ps[4], pq[4];
  const int wid = tid >> 6, lane = tid & 63;
  if (lane == 0) { ps[wid] = s; pq[wid] = q; }
  __syncthreads();
  const float ts = ps[0] + ps[1] + ps[2] + ps[3];
  const float tq = pq[0] + pq[1] + pq[2] + pq[3];
  const float mu = ts * (1.0f / HID);
  const float var = tq * (1.0f / HID) - mu * mu;
  const float rs = rsqrtf(var + 1e-6f);
  const float4 g = ((const float4*)gamma)[tid];
  const float4 bb = ((const float4*)beta)[tid];
  float4 o;
  o.x = (v.x - mu) * rs * g.x + bb.x;
  o.y = (v.y - mu) * rs * g.y + bb.y;
  o.z = (v.z - mu) * rs * g.z + bb.z;
  o.w = (v.w - mu) * rs * g.w + bb.w;
  ((float4*)(y + row * HID))[tid] = o;
}

extern "C" void kernel_launch(void* const* d_in, const int* in_sizes, int n_in,
                              void* d_out, int out_size, void* d_ws, size_t ws_size,
                              hipStream_t stream)
{
  (void)in_sizes; (void)n_in; (void)out_size; (void)ws_size;
  const float* q     = (const float*)d_in[0];
  const float* k     = (const float*)d_in[1];
  const float* v     = (const float*)d_in[2];
  const float* w_qs  = (const float*)d_in[3];
  const float* w_ks  = (const float*)d_in[4];
  const float* w_vs  = (const float*)d_in[5];
  const float* w_fc  = (const float*)d_in[6];
  const float* gamma = (const float*)d_in[7];
  const float* beta  = (const float*)d_in[8];

  char* ws = (char*)d_ws;
  unsigned short* wqt = (unsigned short*)(ws);                      // 4 x 2 MB
  unsigned short* wkt = (unsigned short*)(ws + ((size_t)2 << 20));
  unsigned short* wvt = (unsigned short*)(ws + ((size_t)4 << 20));
  unsigned short* wft = (unsigned short*)(ws + ((size_t)6 << 20));
  unsigned short* qb  = (unsigned short*)(ws + ((size_t)8 << 20));  // 8 MB each
  unsigned short* kb  = (unsigned short*)(ws + ((size_t)16 << 20));
  unsigned short* vb  = (unsigned short*)(ws + ((size_t)24 << 20));
  unsigned short* Qh  = (unsigned short*)(ws + ((size_t)32 << 20));
  unsigned short* Kh  = (unsigned short*)(ws + ((size_t)40 << 20));
  unsigned short* Vt  = (unsigned short*)(ws + ((size_t)48 << 20));
  unsigned short* Ofc = qb;                                         // reuse (dead)
  float*          xres = (float*)(ws + ((size_t)16 << 20));         // reuse kb+vb

  float* y_out = (float*)d_out;
  float* attn  = (float*)d_out + (size_t)NB * SEQ * HID;

  const dim3 b256(256, 1, 1);

  prep<<<dim3(1024, 1, 7), b256, 0, stream>>>(
      w_qs, w_ks, w_vs, w_fc, q, k, v, wqt, wkt, wvt, wft, qb, kb, vb);

  proj_gemm<<<dim3(64, 8, 3), b256, 0, stream>>>(qb, kb, vb, wqt, wkt, wvt, Qh, Kh, Vt);

  fused_attn<<<dim3(16, 32, 1), b256, 0, stream>>>(Qh, Kh, Vt, attn, Ofc);

  fc_gemm<<<dim3(64, 8, 1), b256, 0, stream>>>(Ofc, wft, xres, q);

  ln_kernel<<<dim3(NB * SEQ, 1, 1), b256, 0, stream>>>(xres, gamma, beta, y_out);
}

// Round 10
// 251.553 us; speedup vs baseline: 1.5453x; 1.0155x over previous
//
#include <hip/hip_runtime.h>
#include <stdint.h>

#define NHEADS 16
#define HDIM   64
#define HID    1024
#define SEQ    2048
#define NB     2

typedef short s16x8 __attribute__((ext_vector_type(8)));
typedef float f32x4 __attribute__((ext_vector_type(4)));

// fp32 -> bf16 bits, round-to-nearest-even
__device__ __forceinline__ short f2bf(float f) {
  union { float f; unsigned u; } x; x.f = f;
  unsigned r = (x.u + 0x7FFFu + ((x.u >> 16) & 1u)) >> 16;
  return (short)r;
}

// async global->LDS, 16B per lane; LDS dest = wave base + lane*16, src per-lane
__device__ __forceinline__ void gload16(const void* g, void* l) {
  __builtin_amdgcn_global_load_lds(
      (const __attribute__((address_space(1))) unsigned int*)g,
      (__attribute__((address_space(3))) unsigned int*)l, 16, 0, 0);
}

// ---------------------------------------------------------------------------
// Fused prep: z in [0,4) -> transpose+cast weight z (32x32 LDS tiles);
// z in [4,7) -> cast input z-4 to bf16 (4096 floats/block). [R9-verbatim]
__global__ __launch_bounds__(256)
void prep(const float* __restrict__ w0, const float* __restrict__ w1,
          const float* __restrict__ w2, const float* __restrict__ w3,
          const float* __restrict__ q, const float* __restrict__ k,
          const float* __restrict__ v,
          unsigned short* __restrict__ d0, unsigned short* __restrict__ d1,
          unsigned short* __restrict__ d2, unsigned short* __restrict__ d3,
          unsigned short* __restrict__ qb, unsigned short* __restrict__ kb,
          unsigned short* __restrict__ vb)
{
  const int z = blockIdx.z;
  if (z < 4) {
    const float* src = z == 0 ? w0 : z == 1 ? w1 : z == 2 ? w2 : w3;
    unsigned short* dst = z == 0 ? d0 : z == 1 ? d1 : z == 2 ? d2 : d3;
    __shared__ float t[32][33];
    const int tx = threadIdx.x & 31, ty = threadIdx.x >> 5;
    const int x0 = (blockIdx.x & 31) * 32, y0 = (blockIdx.x >> 5) * 32;
#pragma unroll
    for (int i = 0; i < 4; ++i) {
      const int r = ty + i * 8;
      t[r][tx] = src[(size_t)(y0 + r) * HID + (x0 + tx)];
    }
    __syncthreads();
#pragma unroll
    for (int i = 0; i < 4; ++i) {
      const int r = ty + i * 8;
      dst[(size_t)(x0 + r) * HID + (y0 + tx)] = (unsigned short)f2bf(t[tx][r]);
    }
  } else {
    const float* s = z == 4 ? q : z == 5 ? k : v;
    unsigned short* d = z == 4 ? qb : z == 5 ? kb : vb;
#pragma unroll
    for (int c = 0; c < 2; ++c) {
      const size_t i = (size_t)blockIdx.x * 4096 + c * 2048 + threadIdx.x * 8;
      const float4 f0 = ((const float4*)(s + i))[0];
      const float4 f1 = ((const float4*)(s + i))[1];
      s16x8 o;
      o[0] = f2bf(f0.x); o[1] = f2bf(f0.y); o[2] = f2bf(f0.z); o[3] = f2bf(f0.w);
      o[4] = f2bf(f1.x); o[5] = f2bf(f1.y); o[6] = f2bf(f1.z); o[7] = f2bf(f1.w);
      *(s16x8*)(d + i) = o;
    }
  }
}

// ---------------------------------------------------------------------------
// Projections: 3 GEMMs (z = 0:Q, 1:K, 2:V) in one launch, 128x128 tile (R3's
// proven gemm_bt staging: both operands gload16, acc 4x4, 16 MFMA/wave/K-step)
// + z=3 fusion for TLP: grid (32,8,3) = 768 blocks = 3/CU. 32KB LDS, (256,3).
// z<2: head layout [B][NH][SEQ][HDIM] (Q scaled 0.125); z=2: [B][NH][HDIM][SEQ].
__global__ __launch_bounds__(256, 3)
void proj_gemm(const unsigned short* __restrict__ qb, const unsigned short* __restrict__ kb,
               const unsigned short* __restrict__ vb,
               const unsigned short* __restrict__ wqt, const unsigned short* __restrict__ wkt,
               const unsigned short* __restrict__ wvt,
               unsigned short* __restrict__ Qh, unsigned short* __restrict__ Kh,
               unsigned short* __restrict__ Vt)
{
  __shared__ unsigned short As[128 * 64];
  __shared__ unsigned short Bs[128 * 64];
  const int tid = threadIdx.x, lane = tid & 63, w = tid >> 6;
  const int lg = lane >> 4, ll = lane & 15;
  const int wm = w & 1, wn = w >> 1;
  const int z = blockIdx.z;
  const int m0 = blockIdx.x * 128, n0 = blockIdx.y * 128;
  const int xorv = (ll & 7) << 4;

  const unsigned short* A  = z == 0 ? qb : z == 1 ? kb : vb;
  const unsigned short* Bt = z == 0 ? wqt : z == 1 ? wkt : wvt;
  const float alpha = z == 0 ? 0.125f : 1.0f;

  f32x4 acc[4][4];
#pragma unroll
  for (int m = 0; m < 4; ++m)
#pragma unroll
    for (int n = 0; n < 4; ++n) acc[m][n] = (f32x4)0.f;

  // per-lane staging geometry: call c -> dest byte, row, inverse-swizzled col
  int rS[4], cbS[4];
#pragma unroll
  for (int c = 0; c < 4; ++c) {
    const int b = (w * 4 + c) * 1024 + lane * 16;
    rS[c] = b >> 7;
    cbS[c] = (b & 127) ^ ((rS[c] & 7) << 4);
  }

  for (int k0 = 0; k0 < HID; k0 += 64) {
    __syncthreads();
#pragma unroll
    for (int c = 0; c < 4; ++c) {
      gload16((const char*)A + ((((size_t)(m0 + rS[c]) * HID + k0) << 1) + cbS[c]),
              (char*)As + (w * 4 + c) * 1024);
      gload16((const char*)Bt + ((((size_t)(n0 + rS[c]) * HID + k0) << 1) + cbS[c]),
              (char*)Bs + (w * 4 + c) * 1024);
    }
    __syncthreads();
#pragma unroll
    for (int kk = 0; kk < 2; ++kk) {
      const int cb2 = kk * 64 + lg * 16;
      s16x8 a[4], b[4];
#pragma unroll
      for (int m = 0; m < 4; ++m)
        a[m] = *(const s16x8*)((const char*)As + ((((wm * 64 + m * 16 + ll) << 7) + cb2) ^ xorv));
#pragma unroll
      for (int n = 0; n < 4; ++n)
        b[n] = *(const s16x8*)((const char*)Bs + ((((wn * 64 + n * 16 + ll) << 7) + cb2) ^ xorv));
#pragma unroll
      for (int m = 0; m < 4; ++m)
#pragma unroll
        for (int n = 0; n < 4; ++n)
          acc[m][n] = __builtin_amdgcn_mfma_f32_16x16x32_bf16(a[m], b[n], acc[m][n], 0, 0, 0);
    }
  }

#pragma unroll
  for (int m = 0; m < 4; ++m)
#pragma unroll
    for (int n = 0; n < 4; ++n)
#pragma unroll
      for (int r = 0; r < 4; ++r) {
        const int row = m0 + wm * 64 + m * 16 + lg * 4 + r;
        const int col = n0 + wn * 64 + n * 16 + ll;
        const int bb = row >> 11, l = row & (SEQ - 1);
        const int h = col >> 6, d = col & (HDIM - 1);
        const unsigned short o = (unsigned short)f2bf(acc[m][n][r] * alpha);
        if (z < 2) {
          unsigned short* out = z == 0 ? Qh : Kh;
          out[(((size_t)(bb * NHEADS + h) * SEQ + l) * HDIM) + d] = o;
        } else {
          Vt[(((size_t)(bb * NHEADS + h) * HDIM + d) * SEQ) + l] = o;
        }
      }
}

// FC GEMM: xres = Ofc @ wft^T + resid. BM=64, BN=128, 512 blocks. [R9-verbatim]
__global__ __launch_bounds__(256, 4)
void fc_gemm(const unsigned short* __restrict__ A, const unsigned short* __restrict__ Bt,
             float* __restrict__ C, const float* __restrict__ resid)
{
  __shared__ unsigned short As[64 * 64];
  __shared__ unsigned short Bs[128 * 64];
  const int tid = threadIdx.x, lane = tid & 63, w = tid >> 6;
  const int lg = lane >> 4, ll = lane & 15;
  const int wm = w & 1, wn = w >> 1;
  const int m0 = blockIdx.x * 64, n0 = blockIdx.y * 128;
  const int xorv = (ll & 7) << 4;

  f32x4 acc[2][4];
#pragma unroll
  for (int m = 0; m < 2; ++m)
#pragma unroll
    for (int n = 0; n < 4; ++n) acc[m][n] = (f32x4)0.f;

  int rA[2], cA[2], rB[4], cB[4];
#pragma unroll
  for (int c = 0; c < 2; ++c) {
    const int b = (w * 2 + c) * 1024 + lane * 16;
    rA[c] = b >> 7; cA[c] = (b & 127) ^ ((rA[c] & 7) << 4);
  }
#pragma unroll
  for (int c = 0; c < 4; ++c) {
    const int b = (w * 4 + c) * 1024 + lane * 16;
    rB[c] = b >> 7; cB[c] = (b & 127) ^ ((rB[c] & 7) << 4);
  }

  for (int k0 = 0; k0 < HID; k0 += 64) {
    __syncthreads();
#pragma unroll
    for (int c = 0; c < 2; ++c)
      gload16((const char*)A + ((((size_t)(m0 + rA[c]) * HID + k0) << 1) + cA[c]),
              (char*)As + (w * 2 + c) * 1024);
#pragma unroll
    for (int c = 0; c < 4; ++c)
      gload16((const char*)Bt + ((((size_t)(n0 + rB[c]) * HID + k0) << 1) + cB[c]),
              (char*)Bs + (w * 4 + c) * 1024);
    __syncthreads();
#pragma unroll
    for (int kk = 0; kk < 2; ++kk) {
      const int cb2 = kk * 64 + lg * 16;
      s16x8 a[2], b[4];
#pragma unroll
      for (int m = 0; m < 2; ++m)
        a[m] = *(const s16x8*)((const char*)As + ((((wm * 32 + m * 16 + ll) << 7) + cb2) ^ xorv));
#pragma unroll
      for (int n = 0; n < 4; ++n)
        b[n] = *(const s16x8*)((const char*)Bs + ((((wn * 64 + n * 16 + ll) << 7) + cb2) ^ xorv));
#pragma unroll
      for (int m = 0; m < 2; ++m)
#pragma unroll
        for (int n = 0; n < 4; ++n)
          acc[m][n] = __builtin_amdgcn_mfma_f32_16x16x32_bf16(a[m], b[n], acc[m][n], 0, 0, 0);
    }
  }

#pragma unroll
  for (int m = 0; m < 2; ++m)
#pragma unroll
    for (int n = 0; n < 4; ++n)
#pragma unroll
      for (int r = 0; r < 4; ++r) {
        const int row = m0 + wm * 32 + m * 16 + lg * 4 + r;
        const int col = n0 + wn * 64 + n * 16 + ll;
        const size_t idx = (size_t)row * HID + col;
        C[idx] = acc[m][n][r] + resid[idx];
      }
}

// ---------------------------------------------------------------------------
// Fused attention, 2-pass, sum-only softmax (S ~ N(0,1) by construction,
// exp(s) fp32-safe; math identical to reference's max-shifted softmax).
// Pass 1: QK^T, per-lane exp-sum. Pass 2: recompute, P = exp(s)*inv,
// scalar nontemporal attn store (once), O += P@V via half-chunk wave-private
// Ps. LDS 50KB -> 3 blocks/CU.  [R4-verbatim: known-good 256us config.
// DO NOT add register pressure here: (256,3) is at the VGPR cliff — both
// R5/R8 epilogue experiments (+16 live VGPRs) spilled and cost +130us.]
__global__ __launch_bounds__(256, 3)
void fused_attn(const unsigned short* __restrict__ Qh,
                const unsigned short* __restrict__ Kh,
                const unsigned short* __restrict__ Vt,
                float* __restrict__ attn,
                unsigned short* __restrict__ Ofc)
{
  __shared__ unsigned short Ks[128 * 64];   // 16KB, swizzled
  __shared__ unsigned short Vs[64 * 128];   // 16KB, swizzled (256B rows)
  __shared__ unsigned short Ps[128][72];    // 18KB, 64-key half-chunk
  const int tid = threadIdx.x, lane = tid & 63, w = tid >> 6;
  const int lg = lane >> 4, ll = lane & 15;
  const int xorv = (ll & 7) << 4;

  // bijective XCD remap: each XCD owns 4 heads (K/V L2-resident)
  const int lin = blockIdx.y * gridDim.x + blockIdx.x;
  const int lin2 = (lin & 7) * 64 + (lin >> 3);
  const int z = lin2 >> 4, qb = lin2 & 15;
  const int bb = z >> 4, h = z & 15;
  const int m0 = qb * 128;

  const unsigned short* Qz = Qh + (size_t)z * SEQ * HDIM;
  const unsigned short* Kz = Kh + (size_t)z * SEQ * HDIM;
  const unsigned short* Vz = Vt + (size_t)z * HDIM * SEQ;
  float* Az = attn + (size_t)z * SEQ * SEQ;

  int rK[4], cbK[4], rV[4], cbV[4];
#pragma unroll
  for (int c = 0; c < 4; ++c) {
    const int b = (w * 4 + c) * 1024 + lane * 16;
    rK[c] = b >> 7; cbK[c] = (b & 127) ^ ((rK[c] & 7) << 4);
    rV[c] = b >> 8; cbV[c] = (b & 255) ^ ((rV[c] & 7) << 4);
  }

  // Q fragments (held all kernel)
  s16x8 qf[2][2];
#pragma unroll
  for (int m = 0; m < 2; ++m)
#pragma unroll
    for (int kk = 0; kk < 2; ++kk)
      qf[m][kk] = *(const s16x8*)(Qz + (size_t)(m0 + w * 32 + m * 16 + ll) * HDIM
                                  + kk * 32 + lg * 8);

  float sml[8];
#pragma unroll
  for (int i = 0; i < 8; ++i) sml[i] = 0.f;

  // ---------------- pass 1: per-lane exp-sum ----------------
  for (int j = 0; j < 16; ++j) {
    __syncthreads();
#pragma unroll
    for (int c = 0; c < 4; ++c)
      gload16((const char*)Kz + ((((size_t)(j * 128 + rK[c]) * HDIM) << 1) + cbK[c]),
              (char*)Ks + (w * 4 + c) * 1024);
    __syncthreads();
    f32x4 s[2][8];
#pragma unroll
    for (int m = 0; m < 2; ++m)
#pragma unroll
      for (int n = 0; n < 8; ++n) s[m][n] = (f32x4)0.f;
#pragma unroll
    for (int kk = 0; kk < 2; ++kk) {
      const int cb2 = kk * 64 + lg * 16;
      s16x8 bk[8];
#pragma unroll
      for (int n = 0; n < 8; ++n)
        bk[n] = *(const s16x8*)((const char*)Ks + ((((n * 16 + ll) << 7) + cb2) ^ xorv));
#pragma unroll
      for (int m = 0; m < 2; ++m)
#pragma unroll
        for (int n = 0; n < 8; ++n)
          s[m][n] = __builtin_amdgcn_mfma_f32_16x16x32_bf16(qf[m][kk], bk[n], s[m][n], 0, 0, 0);
    }
#pragma unroll
    for (int m = 0; m < 2; ++m)
#pragma unroll
      for (int r = 0; r < 4; ++r) {
        const int i = m * 4 + r;
#pragma unroll
        for (int n = 0; n < 8; ++n) sml[i] += __expf(s[m][n][r]);
      }
  }
  float inv[8];
#pragma unroll
  for (int i = 0; i < 8; ++i) {
    float su = sml[i];
#pragma unroll
    for (int off = 1; off < 16; off <<= 1) su += __shfl_xor(su, off, 64);
    inv[i] = 1.0f / su;
  }

  f32x4 ao[2][4];
#pragma unroll
  for (int m = 0; m < 2; ++m)
#pragma unroll
    for (int n = 0; n < 4; ++n) ao[m][n] = (f32x4)0.f;

  // ---------------- pass 2: recompute, pack Ps, P@V, nt attn store ----------------
  for (int j = 0; j < 16; ++j) {
    __syncthreads();
#pragma unroll
    for (int c = 0; c < 4; ++c) {
      gload16((const char*)Kz + ((((size_t)(j * 128 + rK[c]) * HDIM) << 1) + cbK[c]),
              (char*)Ks + (w * 4 + c) * 1024);
      gload16((const char*)Vz + ((((size_t)rV[c] * SEQ + j * 128) << 1) + cbV[c]),
              (char*)Vs + (w * 4 + c) * 1024);
    }
    __syncthreads();
    f32x4 s[2][8];
#pragma unroll
    for (int m = 0; m < 2; ++m)
#pragma unroll
      for (int n = 0; n < 8; ++n) s[m][n] = (f32x4)0.f;
#pragma unroll
    for (int kk = 0; kk < 2; ++kk) {
      const int cb2 = kk * 64 + lg * 16;
      s16x8 bk[8];
#pragma unroll
      for (int n = 0; n < 8; ++n)
        bk[n] = *(const s16x8*)((const char*)Ks + ((((n * 16 + ll) << 7) + cb2) ^ xorv));
#pragma unroll
      for (int m = 0; m < 2; ++m)
#pragma unroll
        for (int n = 0; n < 8; ++n)
          s[m][n] = __builtin_amdgcn_mfma_f32_16x16x32_bf16(qf[m][kk], bk[n], s[m][n], 0, 0, 0);
    }
    // two 64-key halves: pack normalized P (bf16) + scalar nt store -> PV MFMA
#pragma unroll
    for (int h2 = 0; h2 < 2; ++h2) {
#pragma unroll
      for (int m = 0; m < 2; ++m)
#pragma unroll
        for (int r = 0; r < 4; ++r) {
          const int i = m * 4 + r;
          const int rowl = w * 32 + m * 16 + lg * 4 + r;
          float* dst = Az + (size_t)(m0 + rowl) * SEQ + j * 128 + h2 * 64 + ll;
#pragma unroll
          for (int nn = 0; nn < 4; ++nn) {
            const float p = __expf(s[m][h2 * 4 + nn][r]) * inv[i];
            __builtin_nontemporal_store(p, dst + nn * 16);
            Ps[rowl][nn * 16 + ll] = (unsigned short)f2bf(p);
          }
        }
      // PV on this half (wave-private Ps rows; no barrier needed)
#pragma unroll
      for (int kkl = 0; kkl < 2; ++kkl) {
        const int cb2v = (h2 * 2 + kkl) * 64 + lg * 16;
        s16x8 pa[2], vbf[4];
#pragma unroll
        for (int m = 0; m < 2; ++m)
          pa[m] = *(const s16x8*)&Ps[w * 32 + m * 16 + ll][kkl * 32 + lg * 8];
#pragma unroll
        for (int n = 0; n < 4; ++n)
          vbf[n] = *(const s16x8*)((const char*)Vs + ((((n * 16 + ll) << 8) + cb2v) ^ xorv));
#pragma unroll
        for (int m = 0; m < 2; ++m)
#pragma unroll
          for (int n = 0; n < 4; ++n)
            ao[m][n] = __builtin_amdgcn_mfma_f32_16x16x32_bf16(pa[m], vbf[n], ao[m][n], 0, 0, 0);
      }
    }
  }

#pragma unroll
  for (int m = 0; m < 2; ++m)
#pragma unroll
    for (int n = 0; n < 4; ++n)
#pragma unroll
      for (int r = 0; r < 4; ++r) {
        const int qrow = m0 + w * 32 + m * 16 + lg * 4 + r;
        const int d = n * 16 + ll;
        Ofc[((size_t)bb * SEQ + qrow) * HID + h * HDIM + d] =
            (unsigned short)f2bf(ao[m][n][r]);
      }
}

// ---------------------------------------------------------------------------
__global__ __launch_bounds__(256)
void ln_kernel(const float* __restrict__ x, const float* __restrict__ gamma,
               const float* __restrict__ beta, float* __restrict__ y)
{
  const int tid = threadIdx.x;
  const size_t row = blockIdx.x;
  const float4 v = ((const float4*)(x + row * HID))[tid];
  float s = v.x + v.y + v.z + v.w;
  float q = v.x * v.x + v.y * v.y + v.z * v.z + v.w * v.w;
#pragma unroll
  for (int off = 32; off; off >>= 1) {
    s += __shfl_xor(s, off, 64);
    q += __shfl_xor(q, off, 64);
  }
  __shared__ float ps[4], pq[4];
  const int wid = tid >> 6, lane = tid & 63;
  if (lane == 0) { ps[wid] = s; pq[wid] = q; }
  __syncthreads();
  const float ts = ps[0] + ps[1] + ps[2] + ps[3];
  const float tq = pq[0] + pq[1] + pq[2] + pq[3];
  const float mu = ts * (1.0f / HID);
  const float var = tq * (1.0f / HID) - mu * mu;
  const float rs = rsqrtf(var + 1e-6f);
  const float4 g = ((const float4*)gamma)[tid];
  const float4 bb = ((const float4*)beta)[tid];
  float4 o;
  o.x = (v.x - mu) * rs * g.x + bb.x;
  o.y = (v.y - mu) * rs * g.y + bb.y;
  o.z = (v.z - mu) * rs * g.z + bb.z;
  o.w = (v.w - mu) * rs * g.w + bb.w;
  ((float4*)(y + row * HID))[tid] = o;
}

extern "C" void kernel_launch(void* const* d_in, const int* in_sizes, int n_in,
                              void* d_out, int out_size, void* d_ws, size_t ws_size,
                              hipStream_t stream)
{
  (void)in_sizes; (void)n_in; (void)out_size; (void)ws_size;
  const float* q     = (const float*)d_in[0];
  const float* k     = (const float*)d_in[1];
  const float* v     = (const float*)d_in[2];
  const float* w_qs  = (const float*)d_in[3];
  const float* w_ks  = (const float*)d_in[4];
  const float* w_vs  = (const float*)d_in[5];
  const float* w_fc  = (const float*)d_in[6];
  const float* gamma = (const float*)d_in[7];
  const float* beta  = (const float*)d_in[8];

  char* ws = (char*)d_ws;
  unsigned short* wqt = (unsigned short*)(ws);                      // 4 x 2 MB
  unsigned short* wkt = (unsigned short*)(ws + ((size_t)2 << 20));
  unsigned short* wvt = (unsigned short*)(ws + ((size_t)4 << 20));
  unsigned short* wft = (unsigned short*)(ws + ((size_t)6 << 20));
  unsigned short* qb  = (unsigned short*)(ws + ((size_t)8 << 20));  // 8 MB each
  unsigned short* kb  = (unsigned short*)(ws + ((size_t)16 << 20));
  unsigned short* vb  = (unsigned short*)(ws + ((size_t)24 << 20));
  unsigned short* Qh  = (unsigned short*)(ws + ((size_t)32 << 20));
  unsigned short* Kh  = (unsigned short*)(ws + ((size_t)40 << 20));
  unsigned short* Vt  = (unsigned short*)(ws + ((size_t)48 << 20));
  unsigned short* Ofc = qb;                                         // reuse (dead)
  float*          xres = (float*)(ws + ((size_t)16 << 20));         // reuse kb+vb

  float* y_out = (float*)d_out;
  float* attn  = (float*)d_out + (size_t)NB * SEQ * HID;

  const dim3 b256(256, 1, 1);

  prep<<<dim3(1024, 1, 7), b256, 0, stream>>>(
      w_qs, w_ks, w_vs, w_fc, q, k, v, wqt, wkt, wvt, wft, qb, kb, vb);

  proj_gemm<<<dim3(32, 8, 3), b256, 0, stream>>>(qb, kb, vb, wqt, wkt, wvt, Qh, Kh, Vt);

  fused_attn<<<dim3(16, 32, 1), b256, 0, stream>>>(Qh, Kh, Vt, attn, Ofc);

  fc_gemm<<<dim3(64, 8, 1), b256, 0, stream>>>(Ofc, wft, xres, q);

  ln_kernel<<<dim3(NB * SEQ, 1, 1), b256, 0, stream>>>(xres, gamma, beta, y_out);
}

// Round 11
// 245.698 us; speedup vs baseline: 1.5821x; 1.0238x over previous
//
#include <hip/hip_runtime.h>
#include <stdint.h>

#define NHEADS 16
#define HDIM   64
#define HID    1024
#define SEQ    2048
#define NB     2

typedef short s16x8 __attribute__((ext_vector_type(8)));
typedef float f32x4 __attribute__((ext_vector_type(4)));

// fp32 -> bf16 bits, round-to-nearest-even
__device__ __forceinline__ short f2bf(float f) {
  union { float f; unsigned u; } x; x.f = f;
  unsigned r = (x.u + 0x7FFFu + ((x.u >> 16) & 1u)) >> 16;
  return (short)r;
}

// async global->LDS, 16B per lane; LDS dest = wave base + lane*16, src per-lane
__device__ __forceinline__ void gload16(const void* g, void* l) {
  __builtin_amdgcn_global_load_lds(
      (const __attribute__((address_space(1))) unsigned int*)g,
      (__attribute__((address_space(3))) unsigned int*)l, 16, 0, 0);
}

// ---------------------------------------------------------------------------
// Fused prep: z in [0,4) -> transpose+cast weight z (32x32 LDS tiles);
// z in [4,7) -> cast input z-4 to bf16 (4096 floats/block). [R9-verbatim]
__global__ __launch_bounds__(256)
void prep(const float* __restrict__ w0, const float* __restrict__ w1,
          const float* __restrict__ w2, const float* __restrict__ w3,
          const float* __restrict__ q, const float* __restrict__ k,
          const float* __restrict__ v,
          unsigned short* __restrict__ d0, unsigned short* __restrict__ d1,
          unsigned short* __restrict__ d2, unsigned short* __restrict__ d3,
          unsigned short* __restrict__ qb, unsigned short* __restrict__ kb,
          unsigned short* __restrict__ vb)
{
  const int z = blockIdx.z;
  if (z < 4) {
    const float* src = z == 0 ? w0 : z == 1 ? w1 : z == 2 ? w2 : w3;
    unsigned short* dst = z == 0 ? d0 : z == 1 ? d1 : z == 2 ? d2 : d3;
    __shared__ float t[32][33];
    const int tx = threadIdx.x & 31, ty = threadIdx.x >> 5;
    const int x0 = (blockIdx.x & 31) * 32, y0 = (blockIdx.x >> 5) * 32;
#pragma unroll
    for (int i = 0; i < 4; ++i) {
      const int r = ty + i * 8;
      t[r][tx] = src[(size_t)(y0 + r) * HID + (x0 + tx)];
    }
    __syncthreads();
#pragma unroll
    for (int i = 0; i < 4; ++i) {
      const int r = ty + i * 8;
      dst[(size_t)(x0 + r) * HID + (y0 + tx)] = (unsigned short)f2bf(t[tx][r]);
    }
  } else {
    const float* s = z == 4 ? q : z == 5 ? k : v;
    unsigned short* d = z == 4 ? qb : z == 5 ? kb : vb;
#pragma unroll
    for (int c = 0; c < 2; ++c) {
      const size_t i = (size_t)blockIdx.x * 4096 + c * 2048 + threadIdx.x * 8;
      const float4 f0 = ((const float4*)(s + i))[0];
      const float4 f1 = ((const float4*)(s + i))[1];
      s16x8 o;
      o[0] = f2bf(f0.x); o[1] = f2bf(f0.y); o[2] = f2bf(f0.z); o[3] = f2bf(f0.w);
      o[4] = f2bf(f1.x); o[5] = f2bf(f1.y); o[6] = f2bf(f1.z); o[7] = f2bf(f1.w);
      *(s16x8*)(d + i) = o;
    }
  }
}

// ---------------------------------------------------------------------------
// Projections: 3 GEMMs (z = 0:Q, 1:K, 2:V), 128x128 tile, 3 blocks/CU. [R10]
__global__ __launch_bounds__(256, 3)
void proj_gemm(const unsigned short* __restrict__ qb, const unsigned short* __restrict__ kb,
               const unsigned short* __restrict__ vb,
               const unsigned short* __restrict__ wqt, const unsigned short* __restrict__ wkt,
               const unsigned short* __restrict__ wvt,
               unsigned short* __restrict__ Qh, unsigned short* __restrict__ Kh,
               unsigned short* __restrict__ Vt)
{
  __shared__ unsigned short As[128 * 64];
  __shared__ unsigned short Bs[128 * 64];
  const int tid = threadIdx.x, lane = tid & 63, w = tid >> 6;
  const int lg = lane >> 4, ll = lane & 15;
  const int wm = w & 1, wn = w >> 1;
  const int z = blockIdx.z;
  const int m0 = blockIdx.x * 128, n0 = blockIdx.y * 128;
  const int xorv = (ll & 7) << 4;

  const unsigned short* A  = z == 0 ? qb : z == 1 ? kb : vb;
  const unsigned short* Bt = z == 0 ? wqt : z == 1 ? wkt : wvt;
  const float alpha = z == 0 ? 0.125f : 1.0f;

  f32x4 acc[4][4];
#pragma unroll
  for (int m = 0; m < 4; ++m)
#pragma unroll
    for (int n = 0; n < 4; ++n) acc[m][n] = (f32x4)0.f;

  int rS[4], cbS[4];
#pragma unroll
  for (int c = 0; c < 4; ++c) {
    const int b = (w * 4 + c) * 1024 + lane * 16;
    rS[c] = b >> 7;
    cbS[c] = (b & 127) ^ ((rS[c] & 7) << 4);
  }

  for (int k0 = 0; k0 < HID; k0 += 64) {
    __syncthreads();
#pragma unroll
    for (int c = 0; c < 4; ++c) {
      gload16((const char*)A + ((((size_t)(m0 + rS[c]) * HID + k0) << 1) + cbS[c]),
              (char*)As + (w * 4 + c) * 1024);
      gload16((const char*)Bt + ((((size_t)(n0 + rS[c]) * HID + k0) << 1) + cbS[c]),
              (char*)Bs + (w * 4 + c) * 1024);
    }
    __syncthreads();
#pragma unroll
    for (int kk = 0; kk < 2; ++kk) {
      const int cb2 = kk * 64 + lg * 16;
      s16x8 a[4], b[4];
#pragma unroll
      for (int m = 0; m < 4; ++m)
        a[m] = *(const s16x8*)((const char*)As + ((((wm * 64 + m * 16 + ll) << 7) + cb2) ^ xorv));
#pragma unroll
      for (int n = 0; n < 4; ++n)
        b[n] = *(const s16x8*)((const char*)Bs + ((((wn * 64 + n * 16 + ll) << 7) + cb2) ^ xorv));
#pragma unroll
      for (int m = 0; m < 4; ++m)
#pragma unroll
        for (int n = 0; n < 4; ++n)
          acc[m][n] = __builtin_amdgcn_mfma_f32_16x16x32_bf16(a[m], b[n], acc[m][n], 0, 0, 0);
    }
  }

#pragma unroll
  for (int m = 0; m < 4; ++m)
#pragma unroll
    for (int n = 0; n < 4; ++n)
#pragma unroll
      for (int r = 0; r < 4; ++r) {
        const int row = m0 + wm * 64 + m * 16 + lg * 4 + r;
        const int col = n0 + wn * 64 + n * 16 + ll;
        const int bb = row >> 11, l = row & (SEQ - 1);
        const int h = col >> 6, d = col & (HDIM - 1);
        const unsigned short o = (unsigned short)f2bf(acc[m][n][r] * alpha);
        if (z < 2) {
          unsigned short* out = z == 0 ? Qh : Kh;
          out[(((size_t)(bb * NHEADS + h) * SEQ + l) * HDIM) + d] = o;
        } else {
          Vt[(((size_t)(bb * NHEADS + h) * HDIM + d) * SEQ) + l] = o;
        }
      }
}

// FC GEMM: xres = Ofc @ wft^T + resid. BM=64, BN=128, 512 blocks. [R9-verbatim]
__global__ __launch_bounds__(256, 4)
void fc_gemm(const unsigned short* __restrict__ A, const unsigned short* __restrict__ Bt,
             float* __restrict__ C, const float* __restrict__ resid)
{
  __shared__ unsigned short As[64 * 64];
  __shared__ unsigned short Bs[128 * 64];
  const int tid = threadIdx.x, lane = tid & 63, w = tid >> 6;
  const int lg = lane >> 4, ll = lane & 15;
  const int wm = w & 1, wn = w >> 1;
  const int m0 = blockIdx.x * 64, n0 = blockIdx.y * 128;
  const int xorv = (ll & 7) << 4;

  f32x4 acc[2][4];
#pragma unroll
  for (int m = 0; m < 2; ++m)
#pragma unroll
    for (int n = 0; n < 4; ++n) acc[m][n] = (f32x4)0.f;

  int rA[2], cA[2], rB[4], cB[4];
#pragma unroll
  for (int c = 0; c < 2; ++c) {
    const int b = (w * 2 + c) * 1024 + lane * 16;
    rA[c] = b >> 7; cA[c] = (b & 127) ^ ((rA[c] & 7) << 4);
  }
#pragma unroll
  for (int c = 0; c < 4; ++c) {
    const int b = (w * 4 + c) * 1024 + lane * 16;
    rB[c] = b >> 7; cB[c] = (b & 127) ^ ((rB[c] & 7) << 4);
  }

  for (int k0 = 0; k0 < HID; k0 += 64) {
    __syncthreads();
#pragma unroll
    for (int c = 0; c < 2; ++c)
      gload16((const char*)A + ((((size_t)(m0 + rA[c]) * HID + k0) << 1) + cA[c]),
              (char*)As + (w * 2 + c) * 1024);
#pragma unroll
    for (int c = 0; c < 4; ++c)
      gload16((const char*)Bt + ((((size_t)(n0 + rB[c]) * HID + k0) << 1) + cB[c]),
              (char*)Bs + (w * 4 + c) * 1024);
    __syncthreads();
#pragma unroll
    for (int kk = 0; kk < 2; ++kk) {
      const int cb2 = kk * 64 + lg * 16;
      s16x8 a[2], b[4];
#pragma unroll
      for (int m = 0; m < 2; ++m)
        a[m] = *(const s16x8*)((const char*)As + ((((wm * 32 + m * 16 + ll) << 7) + cb2) ^ xorv));
#pragma unroll
      for (int n = 0; n < 4; ++n)
        b[n] = *(const s16x8*)((const char*)Bs + ((((wn * 64 + n * 16 + ll) << 7) + cb2) ^ xorv));
#pragma unroll
      for (int m = 0; m < 2; ++m)
#pragma unroll
        for (int n = 0; n < 4; ++n)
          acc[m][n] = __builtin_amdgcn_mfma_f32_16x16x32_bf16(a[m], b[n], acc[m][n], 0, 0, 0);
    }
  }

#pragma unroll
  for (int m = 0; m < 2; ++m)
#pragma unroll
    for (int n = 0; n < 4; ++n)
#pragma unroll
      for (int r = 0; r < 4; ++r) {
        const int row = m0 + wm * 32 + m * 16 + lg * 4 + r;
        const int col = n0 + wn * 64 + n * 16 + ll;
        const size_t idx = (size_t)row * HID + col;
        C[idx] = acc[m][n][r] + resid[idx];
      }
}

// ---------------------------------------------------------------------------
// Fused attention, 2-pass, sum-only softmax. [R4 base; ONE change: pass-1
// K staging double-buffered via LDS union (BufA/BufB also serve as pass-2's
// Ks/Vs) -> one barrier/chunk, next-chunk loads in flight under compute.
// Pass 2 unchanged (both buffers occupied by K+V; no free prefetch target).
// DO NOT add register pressure here: (256,3) is at the VGPR cliff — R5/R8
// epilogue experiments (+16 live VGPRs) spilled and cost +130us.]
__global__ __launch_bounds__(256, 3)
void fused_attn(const unsigned short* __restrict__ Qh,
                const unsigned short* __restrict__ Kh,
                const unsigned short* __restrict__ Vt,
                float* __restrict__ attn,
                unsigned short* __restrict__ Ofc)
{
  __shared__ unsigned short BufA[128 * 64];  // 16KB: pass1 K dbuf0 / pass2 Ks
  __shared__ unsigned short BufB[128 * 64];  // 16KB: pass1 K dbuf1 / pass2 Vs
  __shared__ unsigned short Ps[128][72];     // 18KB, 64-key half-chunk
  const int tid = threadIdx.x, lane = tid & 63, w = tid >> 6;
  const int lg = lane >> 4, ll = lane & 15;
  const int xorv = (ll & 7) << 4;

  // bijective XCD remap: each XCD owns 4 heads (K/V L2-resident)
  const int lin = blockIdx.y * gridDim.x + blockIdx.x;
  const int lin2 = (lin & 7) * 64 + (lin >> 3);
  const int z = lin2 >> 4, qb = lin2 & 15;
  const int bb = z >> 4, h = z & 15;
  const int m0 = qb * 128;

  const unsigned short* Qz = Qh + (size_t)z * SEQ * HDIM;
  const unsigned short* Kz = Kh + (size_t)z * SEQ * HDIM;
  const unsigned short* Vz = Vt + (size_t)z * HDIM * SEQ;
  float* Az = attn + (size_t)z * SEQ * SEQ;

  int rK[4], cbK[4], rV[4], cbV[4];
#pragma unroll
  for (int c = 0; c < 4; ++c) {
    const int b = (w * 4 + c) * 1024 + lane * 16;
    rK[c] = b >> 7; cbK[c] = (b & 127) ^ ((rK[c] & 7) << 4);
    rV[c] = b >> 8; cbV[c] = (b & 255) ^ ((rV[c] & 7) << 4);
  }

  // Q fragments (held all kernel)
  s16x8 qf[2][2];
#pragma unroll
  for (int m = 0; m < 2; ++m)
#pragma unroll
    for (int kk = 0; kk < 2; ++kk)
      qf[m][kk] = *(const s16x8*)(Qz + (size_t)(m0 + w * 32 + m * 16 + ll) * HDIM
                                  + kk * 32 + lg * 8);

  float sml[8];
#pragma unroll
  for (int i = 0; i < 8; ++i) sml[i] = 0.f;

  // ---------------- pass 1: per-lane exp-sum, K double-buffered ----------------
  // prologue: stage chunk 0 into BufA
#pragma unroll
  for (int c = 0; c < 4; ++c)
    gload16((const char*)Kz + ((((size_t)(0 * 128 + rK[c]) * HDIM) << 1) + cbK[c]),
            (char*)BufA + (w * 4 + c) * 1024);
  __syncthreads();
  for (int j = 0; j < 16; ++j) {
    char* cur = (char*)((j & 1) ? BufB : BufA);
    char* nxt = (char*)((j & 1) ? BufA : BufB);
    if (j < 15) {
#pragma unroll
      for (int c = 0; c < 4; ++c)
        gload16((const char*)Kz + ((((size_t)((j + 1) * 128 + rK[c]) * HDIM) << 1) + cbK[c]),
                nxt + (w * 4 + c) * 1024);
    }
    f32x4 s[2][8];
#pragma unroll
    for (int m = 0; m < 2; ++m)
#pragma unroll
      for (int n = 0; n < 8; ++n) s[m][n] = (f32x4)0.f;
#pragma unroll
    for (int kk = 0; kk < 2; ++kk) {
      const int cb2 = kk * 64 + lg * 16;
      s16x8 bk[8];
#pragma unroll
      for (int n = 0; n < 8; ++n)
        bk[n] = *(const s16x8*)(cur + ((((n * 16 + ll) << 7) + cb2) ^ xorv));
#pragma unroll
      for (int m = 0; m < 2; ++m)
#pragma unroll
        for (int n = 0; n < 8; ++n)
          s[m][n] = __builtin_amdgcn_mfma_f32_16x16x32_bf16(qf[m][kk], bk[n], s[m][n], 0, 0, 0);
    }
#pragma unroll
    for (int m = 0; m < 2; ++m)
#pragma unroll
      for (int r = 0; r < 4; ++r) {
        const int i = m * 4 + r;
#pragma unroll
        for (int n = 0; n < 8; ++n) sml[i] += __expf(s[m][n][r]);
      }
    __syncthreads();  // drains nxt loads; protects cur for next-iter staging
  }
  float inv[8];
#pragma unroll
  for (int i = 0; i < 8; ++i) {
    float su = sml[i];
#pragma unroll
    for (int off = 1; off < 16; off <<= 1) su += __shfl_xor(su, off, 64);
    inv[i] = 1.0f / su;
  }

  f32x4 ao[2][4];
#pragma unroll
  for (int m = 0; m < 2; ++m)
#pragma unroll
    for (int n = 0; n < 4; ++n) ao[m][n] = (f32x4)0.f;

  // ---------------- pass 2: recompute, pack Ps, P@V, nt attn store ----------------
  // BufA = Ks, BufB = Vs (V layout: [64][128] rows of 256B, swizzled)
  for (int j = 0; j < 16; ++j) {
    __syncthreads();
#pragma unroll
    for (int c = 0; c < 4; ++c) {
      gload16((const char*)Kz + ((((size_t)(j * 128 + rK[c]) * HDIM) << 1) + cbK[c]),
              (char*)BufA + (w * 4 + c) * 1024);
      gload16((const char*)Vz + ((((size_t)rV[c] * SEQ + j * 128) << 1) + cbV[c]),
              (char*)BufB + (w * 4 + c) * 1024);
    }
    __syncthreads();
    f32x4 s[2][8];
#pragma unroll
    for (int m = 0; m < 2; ++m)
#pragma unroll
      for (int n = 0; n < 8; ++n) s[m][n] = (f32x4)0.f;
#pragma unroll
    for (int kk = 0; kk < 2; ++kk) {
      const int cb2 = kk * 64 + lg * 16;
      s16x8 bk[8];
#pragma unroll
      for (int n = 0; n < 8; ++n)
        bk[n] = *(const s16x8*)((const char*)BufA + ((((n * 16 + ll) << 7) + cb2) ^ xorv));
#pragma unroll
      for (int m = 0; m < 2; ++m)
#pragma unroll
        for (int n = 0; n < 8; ++n)
          s[m][n] = __builtin_amdgcn_mfma_f32_16x16x32_bf16(qf[m][kk], bk[n], s[m][n], 0, 0, 0);
    }
    // two 64-key halves: pack normalized P (bf16) + scalar nt store -> PV MFMA
#pragma unroll
    for (int h2 = 0; h2 < 2; ++h2) {
#pragma unroll
      for (int m = 0; m < 2; ++m)
#pragma unroll
        for (int r = 0; r < 4; ++r) {
          const int i = m * 4 + r;
          const int rowl = w * 32 + m * 16 + lg * 4 + r;
          float* dst = Az + (size_t)(m0 + rowl) * SEQ + j * 128 + h2 * 64 + ll;
#pragma unroll
          for (int nn = 0; nn < 4; ++nn) {
            const float p = __expf(s[m][h2 * 4 + nn][r]) * inv[i];
            __builtin_nontemporal_store(p, dst + nn * 16);
            Ps[rowl][nn * 16 + ll] = (unsigned short)f2bf(p);
          }
        }
      // PV on this half (wave-private Ps rows; no barrier needed)
#pragma unroll
      for (int kkl = 0; kkl < 2; ++kkl) {
        const int cb2v = (h2 * 2 + kkl) * 64 + lg * 16;
        s16x8 pa[2], vbf[4];
#pragma unroll
        for (int m = 0; m < 2; ++m)
          pa[m] = *(const s16x8*)&Ps[w * 32 + m * 16 + ll][kkl * 32 + lg * 8];
#pragma unroll
        for (int n = 0; n < 4; ++n)
          vbf[n] = *(const s16x8*)((const char*)BufB + ((((n * 16 + ll) << 8) + cb2v) ^ xorv));
#pragma unroll
        for (int m = 0; m < 2; ++m)
#pragma unroll
          for (int n = 0; n < 4; ++n)
            ao[m][n] = __builtin_amdgcn_mfma_f32_16x16x32_bf16(pa[m], vbf[n], ao[m][n], 0, 0, 0);
      }
    }
  }

#pragma unroll
  for (int m = 0; m < 2; ++m)
#pragma unroll
    for (int n = 0; n < 4; ++n)
#pragma unroll
      for (int r = 0; r < 4; ++r) {
        const int qrow = m0 + w * 32 + m * 16 + lg * 4 + r;
        const int d = n * 16 + ll;
        Ofc[((size_t)bb * SEQ + qrow) * HID + h * HDIM + d] =
            (unsigned short)f2bf(ao[m][n][r]);
      }
}

// ---------------------------------------------------------------------------
__global__ __launch_bounds__(256)
void ln_kernel(const float* __restrict__ x, const float* __restrict__ gamma,
               const float* __restrict__ beta, float* __restrict__ y)
{
  const int tid = threadIdx.x;
  const size_t row = blockIdx.x;
  const float4 v = ((const float4*)(x + row * HID))[tid];
  float s = v.x + v.y + v.z + v.w;
  float q = v.x * v.x + v.y * v.y + v.z * v.z + v.w * v.w;
#pragma unroll
  for (int off = 32; off; off >>= 1) {
    s += __shfl_xor(s, off, 64);
    q += __shfl_xor(q, off, 64);
  }
  __shared__ float ps[4], pq[4];
  const int wid = tid >> 6, lane = tid & 63;
  if (lane == 0) { ps[wid] = s; pq[wid] = q; }
  __syncthreads();
  const float ts = ps[0] + ps[1] + ps[2] + ps[3];
  const float tq = pq[0] + pq[1] + pq[2] + pq[3];
  const float mu = ts * (1.0f / HID);
  const float var = tq * (1.0f / HID) - mu * mu;
  const float rs = rsqrtf(var + 1e-6f);
  const float4 g = ((const float4*)gamma)[tid];
  const float4 bb = ((const float4*)beta)[tid];
  float4 o;
  o.x = (v.x - mu) * rs * g.x + bb.x;
  o.y = (v.y - mu) * rs * g.y + bb.y;
  o.z = (v.z - mu) * rs * g.z + bb.z;
  o.w = (v.w - mu) * rs * g.w + bb.w;
  ((float4*)(y + row * HID))[tid] = o;
}

extern "C" void kernel_launch(void* const* d_in, const int* in_sizes, int n_in,
                              void* d_out, int out_size, void* d_ws, size_t ws_size,
                              hipStream_t stream)
{
  (void)in_sizes; (void)n_in; (void)out_size; (void)ws_size;
  const float* q     = (const float*)d_in[0];
  const float* k     = (const float*)d_in[1];
  const float* v     = (const float*)d_in[2];
  const float* w_qs  = (const float*)d_in[3];
  const float* w_ks  = (const float*)d_in[4];
  const float* w_vs  = (const float*)d_in[5];
  const float* w_fc  = (const float*)d_in[6];
  const float* gamma = (const float*)d_in[7];
  const float* beta  = (const float*)d_in[8];

  char* ws = (char*)d_ws;
  unsigned short* wqt = (unsigned short*)(ws);                      // 4 x 2 MB
  unsigned short* wkt = (unsigned short*)(ws + ((size_t)2 << 20));
  unsigned short* wvt = (unsigned short*)(ws + ((size_t)4 << 20));
  unsigned short* wft = (unsigned short*)(ws + ((size_t)6 << 20));
  unsigned short* qb  = (unsigned short*)(ws + ((size_t)8 << 20));  // 8 MB each
  unsigned short* kb  = (unsigned short*)(ws + ((size_t)16 << 20));
  unsigned short* vb  = (unsigned short*)(ws + ((size_t)24 << 20));
  unsigned short* Qh  = (unsigned short*)(ws + ((size_t)32 << 20));
  unsigned short* Kh  = (unsigned short*)(ws + ((size_t)40 << 20));
  unsigned short* Vt  = (unsigned short*)(ws + ((size_t)48 << 20));
  unsigned short* Ofc = qb;                                         // reuse (dead)
  float*          xres = (float*)(ws + ((size_t)16 << 20));         // reuse kb+vb

  float* y_out = (float*)d_out;
  float* attn  = (float*)d_out + (size_t)NB * SEQ * HID;

  const dim3 b256(256, 1, 1);

  prep<<<dim3(1024, 1, 7), b256, 0, stream>>>(
      w_qs, w_ks, w_vs, w_fc, q, k, v, wqt, wkt, wvt, wft, qb, kb, vb);

  proj_gemm<<<dim3(32, 8, 3), b256, 0, stream>>>(qb, kb, vb, wqt, wkt, wvt, Qh, Kh, Vt);

  fused_attn<<<dim3(16, 32, 1), b256, 0, stream>>>(Qh, Kh, Vt, attn, Ofc);

  fc_gemm<<<dim3(64, 8, 1), b256, 0, stream>>>(Ofc, wft, xres, q);

  ln_kernel<<<dim3(NB * SEQ, 1, 1), b256, 0, stream>>>(xres, gamma, beta, y_out);
}